// Round 5
// baseline (216.532 us; speedup 1.0000x reference)
//
#include <hip/hip_runtime.h>
#include <stdint.h>

#define NB 8
#define NC 8
#define NN 1024
#define ND 256
#define KK 2048      // NC * ND
#define BM 128
#define BN 64
#define BKK 64
#define NT (KK / BKK)

typedef float f32x4 __attribute__((ext_vector_type(4)));
typedef short bf16x8 __attribute__((ext_vector_type(8)));

__device__ __forceinline__ unsigned short f2bf(float x) {
  union { float f; uint32_t u; } a; a.f = x;
  uint32_t u = a.u;
  return (unsigned short)((u + 0x7FFFu + ((u >> 16) & 1u)) >> 16);  // RTNE
}

__device__ __forceinline__ void gload16(const void* g, void* l) {
  __builtin_amdgcn_global_load_lds(
      (__attribute__((address_space(1))) uint32_t*)g,
      (__attribute__((address_space(3))) uint32_t*)l, 16, 0, 0);
}

// Pass 1: per (b,c,n) row of 256 f32: sq=sum g^2, rnorm=rsqrt(sum g^4);
// ghat[b][n][c*256+d] = bf16(g*rnorm); uFlat[rowid]=sq*rnorm, vFlat[rowid]=rnorm.
// 16 lanes per row, 4 rows per wave in parallel -> 4-step shfl reduce (was
// 4 serial rows x 6-step full-wave reduce).
__global__ __launch_bounds__(256) void prep_kernel(
    const float* __restrict__ g, unsigned short* __restrict__ ghat,
    float* __restrict__ uFlat, float* __restrict__ vFlat) {
  int tid = threadIdx.x;
  int wave = tid >> 6, lane = tid & 63;
  int sub = lane & 15, grp = lane >> 4;
  int rowid = (blockIdx.x * 4 + wave) * 4 + grp;      // 16 rows per block
  const float* row = g + (size_t)rowid * ND;
  f32x4 v[4];
  float s2 = 0.f, s4 = 0.f;
#pragma unroll
  for (int q = 0; q < 4; ++q) {
    v[q] = *(const f32x4*)(row + q * 64 + sub * 4);
#pragma unroll
    for (int e = 0; e < 4; ++e) { float x2 = v[q][e] * v[q][e]; s2 += x2; s4 += x2 * x2; }
  }
#pragma unroll
  for (int off = 8; off; off >>= 1) {                 // reduce within 16-lane group
    s2 += __shfl_xor(s2, off);
    s4 += __shfl_xor(s4, off);
  }
  float rn = rsqrtf(s4);
  int n = rowid & (NN - 1);
  int bc = rowid >> 10;
  int c = bc & (NC - 1);
  int b = bc >> 3;
  unsigned short* dst = ghat + ((size_t)(b * NN + n)) * KK + (size_t)c * ND + sub * 4;
#pragma unroll
  for (int q = 0; q < 4; ++q) {
    ushort4 o;
    o.x = f2bf(v[q][0] * rn); o.y = f2bf(v[q][1] * rn);
    o.z = f2bf(v[q][2] * rn); o.w = f2bf(v[q][3] * rn);
    *(ushort4*)(dst + q * 64) = o;
  }
  if (sub == 0) { uFlat[rowid] = s2 * rn; vFlat[rowid] = rn; }
}

// Pass 2: per b, out = 0.125*(u_n.v_m + v_n.u_m) - 0.25 * <ghat_n, ghat_m>
// Ring-3 LDS pipeline with COUNTED vmcnt (T3/T4): raw s_barrier (no vmcnt(0)
// drain), prefetch 2 tiles deep. Invariants:
//  - step t computes buf[t%3]; stage of tile t+2 targets buf[(t+2)%3] =
//    compute buffer of step t-1, freed by this step's barrier.
//  - per-wave vmcnt(6) (6 loads/tile/thread) + s_barrier ==> ALL waves' tile-t
//    loads are in LDS before any wave reads it.
//  - ds_read results are consumed by MFMA (compiler lgkmcnt) before the wave
//    reaches the next barrier, so DMA into that buffer 2 steps later is safe.
__global__ __launch_bounds__(256) void gram_gemm_kernel(
    const unsigned short* __restrict__ ghat,
    const float* __restrict__ uFlat, const float* __restrict__ vFlat,
    float* __restrict__ out) {
  __shared__ union {
    struct { unsigned short A[3][BM * BKK]; unsigned short Bt[3][BN * BKK]; } s;  // 72 KiB
    struct { float R[128][16]; float Cc[64][16]; } e;                             // 12 KiB
  } sm;

  // XCD swizzle: 1024 blocks, 8 XCDs -> 128 consecutive logical tiles
  // (= one full batch b, one 4MiB ghat panel) per XCD L2.
  int bid = blockIdx.x;
  int logical = (bid & 7) * 128 + (bid >> 3);
  int b = logical >> 7;
  int t7 = logical & 127;
  int row0 = (t7 >> 4) * BM;   // 8 row tiles
  int col0 = (t7 & 15) * BN;   // 16 col tiles
  int tid = threadIdx.x;
  int lane = tid & 63;
  int wave = tid >> 6;
  int wr = (wave >> 1) * 64;   // 2x2 wave grid: 64x32 out per wave
  int wc = (wave & 1) * 32;

  const unsigned short* gA = ghat + (size_t)(b * NN + row0) * KK;
  const unsigned short* gB = ghat + (size_t)(b * NN + col0) * KK;

  f32x4 acc[4][2];
#pragma unroll
  for (int i = 0; i < 4; ++i)
#pragma unroll
    for (int j = 0; j < 2; ++j)
      acc[i][j] = f32x4{0.f, 0.f, 0.f, 0.f};

  int rsel = lane & 15;        // fragment row selector
  int khalf = lane >> 4;       // k-chunk selector
  int r8 = tid >> 3;           // staging row within 32-row group (0..31)
  int s8 = tid & 7;            // staging 16B slot (0..7)

  // 6 global_load_lds per thread per tile (uniform across wave -> vmcnt math).
  auto STAGE = [&](int t, int bi) {
    int k0 = t * BKK;
#pragma unroll
    for (int i = 0; i < 4; ++i) {
      int rr = i * 32 + r8;
      int sg = s8 ^ (rr & 7);  // pre-swizzled global slot (both-sides XOR)
      gload16(gA + (size_t)rr * KK + k0 + sg * 8, &sm.s.A[bi][rr * BKK + s8 * 8]);
    }
#pragma unroll
    for (int i = 0; i < 2; ++i) {
      int rr = i * 32 + r8;
      int sg = s8 ^ (rr & 7);
      gload16(gB + (size_t)rr * KK + k0 + sg * 8, &sm.s.Bt[bi][rr * BKK + s8 * 8]);
    }
  };

  // prologue: tiles 0,1 in flight (12 outstanding per thread)
  STAGE(0, 0);
  STAGE(1, 1);

  int cidx = 0;
  for (int t = 0; t < NT; ++t) {
    if (t + 1 < NT) {
      asm volatile("s_waitcnt vmcnt(6)" ::: "memory");   // tile t done; t+1 may fly
    } else {
      asm volatile("s_waitcnt vmcnt(0)" ::: "memory");   // last tile: full drain
    }
    __builtin_amdgcn_sched_barrier(0);
    __builtin_amdgcn_s_barrier();      // raw barrier: NO implicit vmcnt(0) drain
    __builtin_amdgcn_sched_barrier(0);

    if (t + 2 < NT) {
      int pidx = cidx ? cidx - 1 : 2;  // (t+2)%3: buffer freed by this barrier
      STAGE(t + 2, pidx);
    }

    __builtin_amdgcn_s_setprio(1);
#pragma unroll
    for (int kk = 0; kk < 2; ++kk) {
      bf16x8 af[4], bfb[2];
#pragma unroll
      for (int i = 0; i < 4; ++i) {
        int rr = wr + i * 16 + rsel;
        int slot = (kk * 4 + khalf) ^ (rr & 7);
        af[i] = *(const bf16x8*)&sm.s.A[cidx][rr * BKK + slot * 8];
      }
#pragma unroll
      for (int j = 0; j < 2; ++j) {
        int rr = wc + j * 16 + rsel;
        int slot = (kk * 4 + khalf) ^ (rr & 7);
        bfb[j] = *(const bf16x8*)&sm.s.Bt[cidx][rr * BKK + slot * 8];
      }
#pragma unroll
      for (int i = 0; i < 4; ++i)
#pragma unroll
        for (int j = 0; j < 2; ++j)
          acc[i][j] = __builtin_amdgcn_mfma_f32_16x16x32_bf16(af[i], bfb[j], acc[i][j], 0, 0, 0);
    }
    __builtin_amdgcn_s_setprio(0);

    cidx = (cidx == 2) ? 0 : cidx + 1;
  }
  __syncthreads();   // full drain once, before LDS union reuse

  // Gather u/v (flat layout) into LDS: R[rl][0..7]=u_row, [8..15]=v_row;
  // Cc[cl][0..7]=u_col, [8..15]=v_col.
  {
    int rl = tid >> 1;                 // 0..127
    int half = tid & 1;                // 0 = u, 1 = v
    const float* src = half ? vFlat : uFlat;
#pragma unroll
    for (int c = 0; c < 8; ++c)
      sm.e.R[rl][half * 8 + c] = src[(size_t)(b * NC + c) * NN + row0 + rl];
    if (rl < 64) {
#pragma unroll
      for (int c = 0; c < 8; ++c)
        sm.e.Cc[rl][half * 8 + c] = src[(size_t)(b * NC + c) * NN + col0 + rl];
    }
  }
  __syncthreads();

  int lr = (lane >> 4) * 4;
  int lc = lane & 15;
#pragma unroll
  for (int j = 0; j < 2; ++j) {
    int cl = wc + j * 16 + lc;
    f32x4 uc0 = *(const f32x4*)&sm.e.Cc[cl][0];
    f32x4 uc1 = *(const f32x4*)&sm.e.Cc[cl][4];
    f32x4 vc0 = *(const f32x4*)&sm.e.Cc[cl][8];
    f32x4 vc1 = *(const f32x4*)&sm.e.Cc[cl][12];
#pragma unroll
    for (int i = 0; i < 4; ++i) {
#pragma unroll
      for (int q = 0; q < 4; ++q) {
        int rl = wr + i * 16 + lr + q;
        f32x4 r0 = *(const f32x4*)&sm.e.R[rl][0];
        f32x4 r1 = *(const f32x4*)&sm.e.R[rl][4];
        f32x4 r2 = *(const f32x4*)&sm.e.R[rl][8];
        f32x4 r3 = *(const f32x4*)&sm.e.R[rl][12];
        float fr = r0[0]*vc0[0]+r0[1]*vc0[1]+r0[2]*vc0[2]+r0[3]*vc0[3]
                 + r1[0]*vc1[0]+r1[1]*vc1[1]+r1[2]*vc1[2]+r1[3]*vc1[3]
                 + r2[0]*uc0[0]+r2[1]*uc0[1]+r2[2]*uc0[2]+r2[3]*uc0[3]
                 + r3[0]*uc1[0]+r3[1]*uc1[1]+r3[2]*uc1[2]+r3[3]*uc1[3];
        float val = 0.125f * fr - 0.25f * acc[i][j][q];
        out[((size_t)(b * NN + row0 + rl)) * NN + (size_t)(col0 + cl)] = val;
      }
    }
  }
}

extern "C" void kernel_launch(void* const* d_in, const int* in_sizes, int n_in,
                              void* d_out, int out_size, void* d_ws, size_t ws_size,
                              hipStream_t stream) {
  const float* g = (const float*)d_in[0];
  // d_in[1] = patchPerRow (unused by the reference computation)
  unsigned short* ghat = (unsigned short*)d_ws;                          // 32 MiB bf16
  float* uFlat = (float*)((char*)d_ws + (size_t)NB * NN * KK * 2);       // 256 KiB
  float* vFlat = uFlat + (size_t)NB * NC * NN;                           // 256 KiB
  float* outp = (float*)d_out;

  prep_kernel<<<NB * NC * NN / 16, 256, 0, stream>>>(g, ghat, uFlat, vFlat);
  gram_gemm_kernel<<<1024, 256, 0, stream>>>(ghat, uFlat, vFlat, outp);
}